// Round 2
// baseline (289.810 us; speedup 1.0000x reference)
//
#include <hip/hip_runtime.h>

typedef unsigned short u16t;
typedef __bf16 bf16x8 __attribute__((ext_vector_type(8)));
typedef float  f32x4  __attribute__((ext_vector_type(4)));

#define LRELU_SLOPE 0.01f
#define SAP 136   // LDS row pitch in u16 (128 + 8 pad, keeps 16B alignment)

__device__ __forceinline__ u16t f2b(float f) {
    union { float f; unsigned int i; } x; x.f = f;
    unsigned int r = (x.i + 0x7fffu + ((x.i >> 16) & 1u)) >> 16;
    return (u16t)r;
}
__device__ __forceinline__ float lrelu(float x) { return x >= 0.0f ? x : LRELU_SLOPE * x; }

__device__ __forceinline__ uint4 pack8(float4 x, float4 y) {
    uint4 r;
    r.x = (unsigned)f2b(x.x) | ((unsigned)f2b(x.y) << 16);
    r.y = (unsigned)f2b(x.z) | ((unsigned)f2b(x.w) << 16);
    r.z = (unsigned)f2b(y.x) | ((unsigned)f2b(y.y) << 16);
    r.w = (unsigned)f2b(y.z) | ((unsigned)f2b(y.w) << 16);
    return r;
}

// ---------------------------------------------------------------------------
// Pack ao_W0 [3][128][128] and ao_W1 [3][128][64] (f32) into bf16 MFMA
// B-fragment order: frag element j (0..7) of lane L for (r, kk, coltile c):
//   B[k][n], n = c*16 + (L&15), k = kk*32 + (L>>4)*8 + j
// ---------------------------------------------------------------------------
__global__ void pack_w(const float* __restrict__ W0, const float* __restrict__ W1,
                       u16t* __restrict__ W0p, u16t* __restrict__ W1p) {
    int tid = blockIdx.x * 256 + threadIdx.x;
    if (tid < 3 * 4 * 8 * 64 * 8) {
        int j = tid & 7, lane = (tid >> 3) & 63, c = (tid >> 9) & 7,
            kk = (tid >> 12) & 3, r = tid >> 14;
        int k = kk * 32 + (lane >> 4) * 8 + j;
        int n = c * 16 + (lane & 15);
        W0p[tid] = f2b(W0[(r * 128 + k) * 128 + n]);
    } else {
        int t2 = tid - 3 * 4 * 8 * 64 * 8;
        if (t2 < 3 * 4 * 4 * 64 * 8) {
            int j = t2 & 7, lane = (t2 >> 3) & 63, c = (t2 >> 9) & 3,
                kk = (t2 >> 11) & 3, r = t2 >> 13;
            int k = kk * 32 + (lane >> 4) * 8 + j;
            int n = c * 16 + (lane & 15);
            W1p[t2] = f2b(W1[(r * 128 + k) * 64 + n]);
        }
    }
}

// ---------------------------------------------------------------------------
// Fused kernel: UI MLP (f32 VALU) + relation-sorted AO MLP (bf16 MFMA) + dot.
// 512 blocks x 512 threads (8 waves); each block processes 4 chunks of 128
// (b,n) rows.  Weight fragments live in VGPRs across all chunks.
// ---------------------------------------------------------------------------
#define MFMA_L0(R)                                                             \
    do {                                                                       \
        acc_a = __builtin_amdgcn_mfma_f32_16x16x32_bf16(a0, w0f[R][0], acc_a, 0, 0, 0); \
        acc_a = __builtin_amdgcn_mfma_f32_16x16x32_bf16(a1, w0f[R][1], acc_a, 0, 0, 0); \
        acc_b = __builtin_amdgcn_mfma_f32_16x16x32_bf16(a2, w0f[R][2], acc_b, 0, 0, 0); \
        acc_b = __builtin_amdgcn_mfma_f32_16x16x32_bf16(a3, w0f[R][3], acc_b, 0, 0, 0); \
    } while (0)

#define MFMA_L1(R)                                                             \
    do {                                                                       \
        acc_a = __builtin_amdgcn_mfma_f32_16x16x32_bf16(a0, w1f[R][0], acc_a, 0, 0, 0); \
        acc_a = __builtin_amdgcn_mfma_f32_16x16x32_bf16(a1, w1f[R][1], acc_a, 0, 0, 0); \
        acc_b = __builtin_amdgcn_mfma_f32_16x16x32_bf16(a2, w1f[R][2], acc_b, 0, 0, 0); \
        acc_b = __builtin_amdgcn_mfma_f32_16x16x32_bf16(a3, w1f[R][3], acc_b, 0, 0, 0); \
    } while (0)

__global__ __launch_bounds__(512) void fused_main(
    const float* __restrict__ u_emb, const float* __restrict__ i_emb,
    const float* __restrict__ a_emb, const float* __restrict__ o_emb,
    const int*  __restrict__ s,
    const float* __restrict__ ao_b0, const float* __restrict__ ao_b1,
    const float* __restrict__ uiW0, const float* __restrict__ uib0,
    const float* __restrict__ uiW1, const float* __restrict__ uib1,
    const u16t* __restrict__ W0p, const u16t* __restrict__ W1p,
    float* __restrict__ out)
{
    __shared__ __align__(16) u16t sA[128 * SAP];   // ao_in rows (bf16 bits)
    __shared__ __align__(16) u16t sH[128 * SAP];   // h0 rows   (bf16 bits)
    __shared__ float sUin[4][128];
    __shared__ float sH0[4][128];
    __shared__ float sUI[4][64];
    __shared__ float sPred[128];
    __shared__ int   sS[128];
    __shared__ int   sPerm[128];
    __shared__ int   sCnt[3], sBase[3], sFill[3];
    __shared__ int   sTR[12], sTS[12], sTN[12];
    __shared__ int   sNT;

    const int t    = threadIdx.x;
    const int wave = t >> 6;
    const int lane = t & 63;
    const int m    = lane & 15;
    const int kg   = lane >> 4;
    const int c    = wave;        // layer-0 col tile (0..7)
    const int c2   = wave & 3;    // layer-1 col tile (0..3)
    const int hlf  = wave >> 2;

    // -------- persistent weight fragments (held across all chunks) --------
    bf16x8 w0f[3][4], w1f[3][4];
    float  b0v[3], b1v[3];
#pragma unroll
    for (int r = 0; r < 3; ++r) {
#pragma unroll
        for (int kk = 0; kk < 4; ++kk) {
            w0f[r][kk] = *(const bf16x8*)(W0p + ((((r * 4 + kk) * 8 + c) * 64 + lane) << 3));
            w1f[r][kk] = *(const bf16x8*)(W1p + ((((r * 4 + kk) * 4 + c2) * 64 + lane) << 3));
        }
        b0v[r] = ao_b0[r * 128 + c * 16 + m];
        b1v[r] = ao_b1[r * 64 + c2 * 16 + m];
    }

    for (int cc = 0; cc < 4; ++cc) {
        const int chunk = blockIdx.x * 4 + cc;
        const int R0    = chunk * 128;
        const int B0    = R0 >> 5;     // 4 b's per chunk

        // -------------------- stage (f32 -> bf16) --------------------
        {
            const int row = t >> 2;
            const int d0  = (t & 3) << 4;
            const float* pa = a_emb + (size_t)R0 * 64 + t * 16;
            const float* po = o_emb + (size_t)R0 * 64 + t * 16;
            float4 A0 = ((const float4*)pa)[0], A1 = ((const float4*)pa)[1];
            float4 A2 = ((const float4*)pa)[2], A3 = ((const float4*)pa)[3];
            float4 O0 = ((const float4*)po)[0], O1 = ((const float4*)po)[1];
            float4 O2 = ((const float4*)po)[2], O3 = ((const float4*)po)[3];
            *(uint4*)&sA[row * SAP + d0]          = pack8(A0, A1);
            *(uint4*)&sA[row * SAP + d0 + 8]      = pack8(A2, A3);
            *(uint4*)&sA[row * SAP + 64 + d0]     = pack8(O0, O1);
            *(uint4*)&sA[row * SAP + 64 + d0 + 8] = pack8(O2, O3);
        }
        if (t < 128) {
            int r = s[R0 + t];
            r = r < 0 ? 0 : (r > 2 ? 2 : r);
            sS[t] = r; sPred[t] = 0.0f;
        }
        if (t < 3)   { sCnt[t] = 0; sFill[t] = 0; }
        if (t < 256) {
            int bl = t >> 6, d = t & 63;
            sUin[bl][d] = u_emb[(size_t)(B0 + bl) * 64 + d];
        } else {
            int t2 = t - 256; int bl = t2 >> 6, d = t2 & 63;
            sUin[bl][64 + d] = i_emb[(size_t)(B0 + bl) * 64 + d];
        }
        __syncthreads();

        // -------------------- UI layer 0 (f32 VALU) + histogram ----------
        {
            const int bl = t >> 7, j = t & 127;
            float acc = uib0[j];
#pragma unroll 8
            for (int k = 0; k < 128; ++k) acc += sUin[bl][k] * uiW0[k * 128 + j];
            sH0[bl][j] = lrelu(acc);
        }
        if (t < 128) atomicAdd(&sCnt[sS[t]], 1);
        __syncthreads();

        // -------------------- UI layer 1 (f32 VALU) --------------------
        if (t < 256) {
            const int bl = t >> 6, j = t & 63;
            float acc = uib1[j];
#pragma unroll 8
            for (int k = 0; k < 128; ++k) acc += sH0[bl][k] * uiW1[k * 64 + j];
            sUI[bl][j] = lrelu(acc);
        }
        // -------------------- build relation-sorted tiles --------------------
        if (t == 0) {
            int pos = 0, nt = 0;
            for (int r = 0; r < 3; ++r) {
                sBase[r] = pos;
                const int n = sCnt[r];
                for (int i = 0; i < n; i += 16) {
                    sTR[nt] = r; sTS[nt] = pos + i;
                    sTN[nt] = (n - i < 16) ? (n - i) : 16; ++nt;
                }
                pos += n;
            }
            sNT = nt;
        }
        __syncthreads();
        if (t < 128) { int r = sS[t]; sPerm[sBase[r] + atomicAdd(&sFill[r], 1)] = t; }
        __syncthreads();

        const int NT = sNT;

        // ---- layer 0 MFMA: h0 = lrelu(ao_in @ W0[r] + b0) -> sH (bf16) ----
        for (int mt = 0; mt < NT; ++mt) {
            const int r = sTR[mt], st = sTS[mt], nr = sTN[mt];
            const int lrow = sPerm[st + (m < nr ? m : nr - 1)];
            const u16t* ap = &sA[lrow * SAP + kg * 8];
            bf16x8 a0 = *(const bf16x8*)(ap);
            bf16x8 a1 = *(const bf16x8*)(ap + 32);
            bf16x8 a2 = *(const bf16x8*)(ap + 64);
            bf16x8 a3 = *(const bf16x8*)(ap + 96);
            f32x4 acc_a = {0.f, 0.f, 0.f, 0.f};
            f32x4 acc_b = {0.f, 0.f, 0.f, 0.f};
            if (r == 0)      { MFMA_L0(0); }
            else if (r == 1) { MFMA_L0(1); }
            else             { MFMA_L0(2); }
            f32x4 acc = acc_a + acc_b;
            const float bias = (r == 0) ? b0v[0] : (r == 1) ? b0v[1] : b0v[2];
#pragma unroll
            for (int j = 0; j < 4; ++j) {
                const int rj = kg * 4 + j;
                if (rj < nr) {
                    sH[sPerm[st + rj] * SAP + c * 16 + m] = f2b(lrelu(acc[j] + bias));
                }
            }
        }
        __syncthreads();

        // ---- layer 1 MFMA + bias + lrelu + dot(ui, h1) -> sPred ----
        for (int mt = hlf; mt < NT; mt += 2) {
            const int r = sTR[mt], st = sTS[mt], nr = sTN[mt];
            const int lrow = sPerm[st + (m < nr ? m : nr - 1)];
            const u16t* hp = &sH[lrow * SAP + kg * 8];
            bf16x8 a0 = *(const bf16x8*)(hp);
            bf16x8 a1 = *(const bf16x8*)(hp + 32);
            bf16x8 a2 = *(const bf16x8*)(hp + 64);
            bf16x8 a3 = *(const bf16x8*)(hp + 96);
            f32x4 acc_a = {0.f, 0.f, 0.f, 0.f};
            f32x4 acc_b = {0.f, 0.f, 0.f, 0.f};
            if (r == 0)      { MFMA_L1(0); }
            else if (r == 1) { MFMA_L1(1); }
            else             { MFMA_L1(2); }
            f32x4 acc = acc_a + acc_b;
            const float bias = (r == 0) ? b1v[0] : (r == 1) ? b1v[1] : b1v[2];
            const int o = c2 * 16 + m;
            float pj[4];
#pragma unroll
            for (int j = 0; j < 4; ++j) {
                const int rj  = kg * 4 + j;
                const int lr2 = sPerm[st + (rj < nr ? rj : nr - 1)];
                pj[j] = lrelu(acc[j] + bias) * sUI[lr2 >> 5][o];
            }
#pragma unroll
            for (int msk = 8; msk >= 1; msk >>= 1) {
#pragma unroll
                for (int j = 0; j < 4; ++j) pj[j] += __shfl_xor(pj[j], msk, 16);
            }
            if (m == 0) {
#pragma unroll
                for (int j = 0; j < 4; ++j) {
                    const int rj = kg * 4 + j;
                    if (rj < nr) atomicAdd(&sPred[sPerm[st + rj]], pj[j]);
                }
            }
        }
        __syncthreads();
        if (t < 128) out[R0 + t] = sPred[t];
        __syncthreads();
    }
}

extern "C" void kernel_launch(void* const* d_in, const int* in_sizes, int n_in,
                              void* d_out, int out_size, void* d_ws, size_t ws_size,
                              hipStream_t stream) {
    (void)in_sizes; (void)n_in; (void)out_size; (void)ws_size;
    const float* u_emb = (const float*)d_in[0];
    const float* i_emb = (const float*)d_in[1];
    const float* a_emb = (const float*)d_in[2];
    const float* o_emb = (const float*)d_in[3];
    const int*   s     = (const int*)  d_in[4];
    const float* aoW0  = (const float*)d_in[5];
    const float* aob0  = (const float*)d_in[6];
    const float* aoW1  = (const float*)d_in[7];
    const float* aob1  = (const float*)d_in[8];
    const float* uiW0  = (const float*)d_in[9];
    const float* uib0  = (const float*)d_in[10];
    const float* uiW1  = (const float*)d_in[11];
    const float* uib1  = (const float*)d_in[12];
    float* out = (float*)d_out;

    u16t* W0p = (u16t*)d_ws;            // 49152 elems
    u16t* W1p = W0p + 49152;            // 24576 elems

    pack_w<<<dim3(288), dim3(256), 0, stream>>>(aoW0, aoW1, W0p, W1p);
    fused_main<<<dim3(512), dim3(512), 0, stream>>>(
        u_emb, i_emb, a_emb, o_emb, s, aob0, aob1,
        uiW0, uib0, uiW1, uib1, W0p, W1p, out);
}

// Round 3
// 260.601 us; speedup vs baseline: 1.1121x; 1.1121x over previous
//
#include <hip/hip_runtime.h>

typedef unsigned short u16t;
typedef __bf16 bf16x8 __attribute__((ext_vector_type(8)));
typedef float  f32x4  __attribute__((ext_vector_type(4)));

#define SLOPE 0.01f
#define SAP 136   // LDS row pitch in u16 (128 + 8 pad; 272 B = 17*16 keeps 16B align)

__device__ __forceinline__ float lrelu(float x) { return x >= 0.0f ? x : SLOPE * x; }
__device__ __forceinline__ u16t f2b(float f) {
    union { float f; unsigned i; } x; x.f = f;
    return (u16t)((x.i + 0x7fffu + ((x.i >> 16) & 1u)) >> 16);
}
__device__ __forceinline__ unsigned pk2(float a, float b) {
    union { float f; unsigned i; } xa, xb; xa.f = a; xb.f = b;
    unsigned ra = (xa.i + 0x7fffu + ((xa.i >> 16) & 1u)) >> 16;
    unsigned rb = (xb.i + 0x7fffu + ((xb.i >> 16) & 1u)) & 0xffff0000u;
    return ra | rb;
}
__device__ __forceinline__ uint4 pack8(float4 x, float4 y) {
    uint4 r; r.x = pk2(x.x, x.y); r.y = pk2(x.z, x.w);
    r.z = pk2(y.x, y.y); r.w = pk2(y.z, y.w); return r;
}

// ---------------------------------------------------------------------------
// Pack ao_W0 [3][128][128], ao_W1 [3][128][64] (f32) -> bf16 MFMA B-fragments:
// frag elem j of lane L for (r,kk,c): B[k][n], n=c*16+(L&15), k=kk*32+(L>>4)*8+j
// ---------------------------------------------------------------------------
__global__ void pack_w(const float* __restrict__ W0, const float* __restrict__ W1,
                       u16t* __restrict__ W0p, u16t* __restrict__ W1p) {
    int tid = blockIdx.x * 256 + threadIdx.x;
    if (tid < 3 * 4 * 8 * 64 * 8) {
        int j = tid & 7, lane = (tid >> 3) & 63, c = (tid >> 9) & 7,
            kk = (tid >> 12) & 3, r = tid >> 14;
        int k = kk * 32 + (lane >> 4) * 8 + j;
        int n = c * 16 + (lane & 15);
        W0p[tid] = f2b(W0[(r * 128 + k) * 128 + n]);
    } else {
        int t2 = tid - 3 * 4 * 8 * 64 * 8;
        if (t2 < 3 * 4 * 4 * 64 * 8) {
            int j = t2 & 7, lane = (t2 >> 3) & 63, c = (t2 >> 9) & 3,
                kk = (t2 >> 11) & 3, r = t2 >> 13;
            int k = kk * 32 + (lane >> 4) * 8 + j;
            int n = c * 16 + (lane & 15);
            W1p[t2] = f2b(W1[(r * 128 + k) * 64 + n]);
        }
    }
}

// ---------------------------------------------------------------------------
// UI branch via MFMA: ui[8192][64] (f32) -> ws.  64 blocks x 512 thr,
// one 128-row chunk each.
// ---------------------------------------------------------------------------
__global__ __launch_bounds__(512) void prep_ui(
    const float* __restrict__ u_emb, const float* __restrict__ i_emb,
    const float* __restrict__ uiW0, const float* __restrict__ uib0,
    const float* __restrict__ uiW1, const float* __restrict__ uib1,
    float* __restrict__ ui)
{
    __shared__ __align__(16) u16t sA[128 * SAP];
    __shared__ __align__(16) u16t sH[128 * SAP];
    const int t = threadIdx.x, wave = t >> 6, lane = t & 63, m = lane & 15, kg = lane >> 4;
    const int c = wave, c2 = wave & 3, hlf = wave >> 2;
    const int B0 = blockIdx.x * 128;

    bf16x8 w0f[4], w1f[4];
#pragma unroll
    for (int kk = 0; kk < 4; ++kk) {
        union { u16t u[8]; bf16x8 v; } t0, t1;
#pragma unroll
        for (int j = 0; j < 8; ++j) {
            int k = kk * 32 + kg * 8 + j;
            t0.u[j] = f2b(uiW0[k * 128 + c * 16 + m]);
            t1.u[j] = f2b(uiW1[k * 64 + c2 * 16 + m]);
        }
        w0f[kk] = t0.v; w1f[kk] = t1.v;
    }
    const float b0 = uib0[c * 16 + m], b1 = uib1[c2 * 16 + m];

    {   // stage: rows = b, cols = u||i
        const int row = t >> 2, seg = t & 3;
        const float* src = (seg < 2) ? (u_emb + (size_t)(B0 + row) * 64 + seg * 32)
                                     : (i_emb + (size_t)(B0 + row) * 64 + (seg - 2) * 32);
        float4 v0 = ((const float4*)src)[0], v1 = ((const float4*)src)[1];
        float4 v2 = ((const float4*)src)[2], v3 = ((const float4*)src)[3];
        float4 v4 = ((const float4*)src)[4], v5 = ((const float4*)src)[5];
        float4 v6 = ((const float4*)src)[6], v7 = ((const float4*)src)[7];
        uint4* dst = (uint4*)&sA[row * SAP + seg * 32];
        dst[0] = pack8(v0, v1); dst[1] = pack8(v2, v3);
        dst[2] = pack8(v4, v5); dst[3] = pack8(v6, v7);
    }
    __syncthreads();

#pragma unroll
    for (int mt = 0; mt < 8; ++mt) {
        const u16t* ap = &sA[(mt * 16 + m) * SAP + kg * 8];
        bf16x8 a0 = *(const bf16x8*)(ap),      a1 = *(const bf16x8*)(ap + 32);
        bf16x8 a2 = *(const bf16x8*)(ap + 64), a3 = *(const bf16x8*)(ap + 96);
        f32x4 acc = {0.f, 0.f, 0.f, 0.f};
        acc = __builtin_amdgcn_mfma_f32_16x16x32_bf16(a0, w0f[0], acc, 0, 0, 0);
        acc = __builtin_amdgcn_mfma_f32_16x16x32_bf16(a1, w0f[1], acc, 0, 0, 0);
        acc = __builtin_amdgcn_mfma_f32_16x16x32_bf16(a2, w0f[2], acc, 0, 0, 0);
        acc = __builtin_amdgcn_mfma_f32_16x16x32_bf16(a3, w0f[3], acc, 0, 0, 0);
#pragma unroll
        for (int j = 0; j < 4; ++j)
            sH[(mt * 16 + kg * 4 + j) * SAP + c * 16 + m] = f2b(lrelu(acc[j] + b0));
    }
    __syncthreads();

    for (int mt = hlf; mt < 8; mt += 2) {
        const u16t* hp = &sH[(mt * 16 + m) * SAP + kg * 8];
        bf16x8 a0 = *(const bf16x8*)(hp),      a1 = *(const bf16x8*)(hp + 32);
        bf16x8 a2 = *(const bf16x8*)(hp + 64), a3 = *(const bf16x8*)(hp + 96);
        f32x4 acc = {0.f, 0.f, 0.f, 0.f};
        acc = __builtin_amdgcn_mfma_f32_16x16x32_bf16(a0, w1f[0], acc, 0, 0, 0);
        acc = __builtin_amdgcn_mfma_f32_16x16x32_bf16(a1, w1f[1], acc, 0, 0, 0);
        acc = __builtin_amdgcn_mfma_f32_16x16x32_bf16(a2, w1f[2], acc, 0, 0, 0);
        acc = __builtin_amdgcn_mfma_f32_16x16x32_bf16(a3, w1f[3], acc, 0, 0, 0);
#pragma unroll
        for (int j = 0; j < 4; ++j)
            ui[(size_t)(B0 + mt * 16 + kg * 4 + j) * 64 + c2 * 16 + m] = lrelu(acc[j] + b1);
    }
}

// ---------------------------------------------------------------------------
// AO branch: ballot-sort rows by relation BEFORE staging (LDS holds sorted
// rows -> contiguous MFMA fragment reads), then L0/L1 MFMA + fused dot.
// 1024 blocks x 512 thr, 4 chunks of 64 rows each; double-buffered metadata.
// ---------------------------------------------------------------------------
#define MFMA_L0(R)                                                             \
    do {                                                                       \
        acc_a = __builtin_amdgcn_mfma_f32_16x16x32_bf16(a0, w0f[R][0], acc_a, 0, 0, 0); \
        acc_a = __builtin_amdgcn_mfma_f32_16x16x32_bf16(a1, w0f[R][1], acc_a, 0, 0, 0); \
        acc_b = __builtin_amdgcn_mfma_f32_16x16x32_bf16(a2, w0f[R][2], acc_b, 0, 0, 0); \
        acc_b = __builtin_amdgcn_mfma_f32_16x16x32_bf16(a3, w0f[R][3], acc_b, 0, 0, 0); \
    } while (0)
#define MFMA_L1(R)                                                             \
    do {                                                                       \
        acc_a = __builtin_amdgcn_mfma_f32_16x16x32_bf16(a0, w1f[R][0], acc_a, 0, 0, 0); \
        acc_a = __builtin_amdgcn_mfma_f32_16x16x32_bf16(a1, w1f[R][1], acc_a, 0, 0, 0); \
        acc_b = __builtin_amdgcn_mfma_f32_16x16x32_bf16(a2, w1f[R][2], acc_b, 0, 0, 0); \
        acc_b = __builtin_amdgcn_mfma_f32_16x16x32_bf16(a3, w1f[R][3], acc_b, 0, 0, 0); \
    } while (0)

__global__ __launch_bounds__(512, 4) void ao_main(
    const float* __restrict__ a_emb, const float* __restrict__ o_emb,
    const int*  __restrict__ s,
    const float* __restrict__ ao_b0, const float* __restrict__ ao_b1,
    const u16t* __restrict__ W0p, const u16t* __restrict__ W1p,
    const float* __restrict__ ui,
    float* __restrict__ out)
{
    __shared__ __align__(16) u16t sA[64 * SAP];
    __shared__ __align__(16) u16t sH[64 * SAP];
    __shared__ float sUI[2][2][64];
    __shared__ float sPred[2][64];
    __shared__ int   sPerm[2][64], sBl[2][64];
    __shared__ int   sTR[2][6], sTS[2][6], sTN[2][6], sNT[2];

    const int t = threadIdx.x, wave = t >> 6, lane = t & 63, m = lane & 15, kg = lane >> 4;
    const int c = wave, c2 = wave & 3, hlf = wave >> 2;

    bf16x8 w0f[3][4], w1f[3][4];
    float  b0v[3], b1v[3];
#pragma unroll
    for (int r = 0; r < 3; ++r) {
#pragma unroll
        for (int kk = 0; kk < 4; ++kk) {
            w0f[r][kk] = *(const bf16x8*)(W0p + ((((r * 4 + kk) * 8 + c) * 64 + lane) << 3));
            w1f[r][kk] = *(const bf16x8*)(W1p + ((((r * 4 + kk) * 4 + c2) * 64 + lane) << 3));
        }
        b0v[r] = ao_b0[r * 128 + c * 16 + m];
        b1v[r] = ao_b1[r * 64 + c2 * 16 + m];
    }

    for (int cc = 0; cc < 4; ++cc) {
        const int p     = cc & 1;
        const int chunk = blockIdx.x * 4 + cc;
        const int R0    = chunk * 64;

        // ---- phase A: wave0 ballot-sort | init | write-out of prev chunk ----
        if (t < 64) {
            int sv = s[R0 + t];
            sv = sv < 0 ? 0 : (sv > 2 ? 2 : sv);
            unsigned long long m0 = __ballot(sv == 0);
            unsigned long long m1 = __ballot(sv == 1);
            unsigned long long m2 = __ballot(sv == 2);
            int n0 = __popcll(m0), n1 = __popcll(m1), n2 = __popcll(m2);
            unsigned long long below = (1ull << t) - 1ull;
            unsigned long long mm = sv == 0 ? m0 : (sv == 1 ? m1 : m2);
            int bs = sv == 0 ? 0 : (sv == 1 ? n0 : n0 + n1);
            int q = bs + __popcll(mm & below);
            sPerm[p][q] = t;
            sBl[p][q]   = t >> 5;
            int t0 = (n0 + 15) >> 4, t1 = (n1 + 15) >> 4, t2 = (n2 + 15) >> 4;
            if (t == 0) sNT[p] = t0 + t1 + t2;
            if (t < t0 + t1 + t2) {
                int r, idx;
                if (t < t0)           { r = 0; idx = t; }
                else if (t < t0 + t1) { r = 1; idx = t - t0; }
                else                  { r = 2; idx = t - t0 - t1; }
                int cb = r == 0 ? 0  : (r == 1 ? n0 : n0 + n1);
                int cn = r == 0 ? n0 : (r == 1 ? n1 : n2);
                int rem = cn - idx * 16;
                sTR[p][t] = r; sTS[p][t] = cb + idx * 16;
                sTN[p][t] = rem < 16 ? rem : 16;
            }
        } else if (t < 128) {
            sPred[p][t - 64] = 0.0f;
        } else if (t < 256) {
            int j = t - 128;
            sUI[p][j >> 6][j & 63] = ui[(size_t)(R0 >> 5) * 64 + j];
        } else if (t < 320 && cc > 0) {
            int j = t - 256;
            out[R0 - 64 + sPerm[1 - p][j]] = sPred[1 - p][j];
        }
        __syncthreads();

        // ---- stage: gather rows in sorted order, f32 -> bf16 ----
        {
            const int q = t >> 3, seg = t & 7;
            const int grow = R0 + sPerm[p][q];
            const float* src = (seg < 4) ? (a_emb + (size_t)grow * 64 + seg * 16)
                                         : (o_emb + (size_t)grow * 64 + (seg - 4) * 16);
            float4 v0 = ((const float4*)src)[0], v1 = ((const float4*)src)[1];
            float4 v2 = ((const float4*)src)[2], v3 = ((const float4*)src)[3];
            uint4* dst = (uint4*)&sA[q * SAP + seg * 16];
            dst[0] = pack8(v0, v1);
            dst[1] = pack8(v2, v3);
        }
        __syncthreads();

        const int NT = sNT[p];

        // ---- L0 MFMA: h0 = lrelu(ao_in @ W0[r] + b0) -> sH (tile-sorted) ----
        for (int mt = 0; mt < NT; ++mt) {
            const int r = sTR[p][mt], st = sTS[p][mt], nr = sTN[p][mt];
            const int lr = st + (m < nr ? m : nr - 1);
            const u16t* ap = &sA[lr * SAP + kg * 8];
            bf16x8 a0 = *(const bf16x8*)(ap),      a1 = *(const bf16x8*)(ap + 32);
            bf16x8 a2 = *(const bf16x8*)(ap + 64), a3 = *(const bf16x8*)(ap + 96);
            f32x4 acc_a = {0.f, 0.f, 0.f, 0.f}, acc_b = {0.f, 0.f, 0.f, 0.f};
            if (r == 0)      { MFMA_L0(0); }
            else if (r == 1) { MFMA_L0(1); }
            else             { MFMA_L0(2); }
            f32x4 acc = acc_a + acc_b;
            const float bias = r == 0 ? b0v[0] : (r == 1 ? b0v[1] : b0v[2]);
#pragma unroll
            for (int j = 0; j < 4; ++j) {
                const int rj = kg * 4 + j;
                if (rj < nr) sH[(st + rj) * SAP + c * 16 + m] = f2b(lrelu(acc[j] + bias));
            }
        }
        __syncthreads();

        // ---- L1 MFMA + bias + lrelu + dot(ui, h1) -> sPred ----
        for (int mt = hlf; mt < NT; mt += 2) {
            const int r = sTR[p][mt], st = sTS[p][mt], nr = sTN[p][mt];
            const int lr = st + (m < nr ? m : nr - 1);
            const u16t* hp = &sH[lr * SAP + kg * 8];
            bf16x8 a0 = *(const bf16x8*)(hp),      a1 = *(const bf16x8*)(hp + 32);
            bf16x8 a2 = *(const bf16x8*)(hp + 64), a3 = *(const bf16x8*)(hp + 96);
            f32x4 acc_a = {0.f, 0.f, 0.f, 0.f}, acc_b = {0.f, 0.f, 0.f, 0.f};
            if (r == 0)      { MFMA_L1(0); }
            else if (r == 1) { MFMA_L1(1); }
            else             { MFMA_L1(2); }
            f32x4 acc = acc_a + acc_b;
            const float bias = r == 0 ? b1v[0] : (r == 1 ? b1v[1] : b1v[2]);
            const int o = c2 * 16 + m;
            float pj[4];
#pragma unroll
            for (int j = 0; j < 4; ++j) {
                const int rj = kg * 4 + j;
                const int rq = st + (rj < nr ? rj : nr - 1);
                pj[j] = lrelu(acc[j] + bias) * sUI[p][sBl[p][rq]][o];
            }
#pragma unroll
            for (int msk = 8; msk >= 1; msk >>= 1) {
#pragma unroll
                for (int j = 0; j < 4; ++j) pj[j] += __shfl_xor(pj[j], msk, 16);
            }
            if (m == 0) {
#pragma unroll
                for (int j = 0; j < 4; ++j) {
                    const int rj = kg * 4 + j;
                    if (rj < nr) atomicAdd(&sPred[p][st + rj], pj[j]);
                }
            }
        }
        __syncthreads();
    }
    // final chunk (cc=3, p=1) write-out
    if (t < 64) out[blockIdx.x * 256 + 192 + sPerm[1][t]] = sPred[1][t];
}

extern "C" void kernel_launch(void* const* d_in, const int* in_sizes, int n_in,
                              void* d_out, int out_size, void* d_ws, size_t ws_size,
                              hipStream_t stream) {
    (void)in_sizes; (void)n_in; (void)out_size; (void)ws_size;
    const float* u_emb = (const float*)d_in[0];
    const float* i_emb = (const float*)d_in[1];
    const float* a_emb = (const float*)d_in[2];
    const float* o_emb = (const float*)d_in[3];
    const int*   s     = (const int*)  d_in[4];
    const float* aoW0  = (const float*)d_in[5];
    const float* aob0  = (const float*)d_in[6];
    const float* aoW1  = (const float*)d_in[7];
    const float* aob1  = (const float*)d_in[8];
    const float* uiW0  = (const float*)d_in[9];
    const float* uib0  = (const float*)d_in[10];
    const float* uiW1  = (const float*)d_in[11];
    const float* uib1  = (const float*)d_in[12];
    float* out = (float*)d_out;

    u16t*  W0p = (u16t*)d_ws;                       // 49152 u16
    u16t*  W1p = W0p + 49152;                       // 24576 u16
    float* ui  = (float*)((char*)d_ws + 147456);    // 8192*64 f32 = 2 MB

    pack_w<<<dim3(288), dim3(256), 0, stream>>>(aoW0, aoW1, W0p, W1p);
    prep_ui<<<dim3(64), dim3(512), 0, stream>>>(u_emb, i_emb, uiW0, uib0, uiW1, uib1, ui);
    ao_main<<<dim3(1024), dim3(512), 0, stream>>>(
        a_emb, o_emb, s, aob0, aob1, W0p, W1p, ui, out);
}

// Round 5
// 215.931 us; speedup vs baseline: 1.3421x; 1.2069x over previous
//
#include <hip/hip_runtime.h>

typedef unsigned short u16t;
typedef __bf16 bf16x8 __attribute__((ext_vector_type(8)));
typedef float  f32x4  __attribute__((ext_vector_type(4)));

#define SLOPE 0.01f
#define SAP 136   // LDS pitch (u16) for 128-col rows: 272 B, 16B-aligned
#define UIP 72    // LDS pitch (u16) for 64-col ui rows: 144 B, 16B-aligned

__device__ __forceinline__ float lrelu(float x) { return x >= 0.0f ? x : SLOPE * x; }
__device__ __forceinline__ u16t f2b(float f) {
    union { float f; unsigned i; } x; x.f = f;
    return (u16t)((x.i + 0x7fffu + ((x.i >> 16) & 1u)) >> 16);
}
__device__ __forceinline__ float b2f(u16t u) {
    union { unsigned i; float f; } x; x.i = ((unsigned)u) << 16; return x.f;
}
__device__ __forceinline__ unsigned pk2(float a, float b) {
    union { float f; unsigned i; } xa, xb; xa.f = a; xb.f = b;
    unsigned ra = (xa.i + 0x7fffu + ((xa.i >> 16) & 1u)) >> 16;
    unsigned rb = (xb.i + 0x7fffu + ((xb.i >> 16) & 1u)) & 0xffff0000u;
    return ra | rb;
}
__device__ __forceinline__ uint4 pack8(float4 x, float4 y) {
    uint4 r; r.x = pk2(x.x, x.y); r.y = pk2(x.z, x.w);
    r.z = pk2(y.x, y.y); r.w = pk2(y.z, y.w); return r;
}
__device__ __forceinline__ int clmp3(int v) { return v < 0 ? 0 : (v > 2 ? 2 : v); }

// ---------------------------------------------------------------------------
// Pack AO + UI weights (f32) into bf16 MFMA B-fragment order:
// frag elem j of lane L for (kk, coltile c): B[k][n], n=c*16+(L&15),
// k=kk*32+(L>>4)*8+j.   W0p: r*16384 per relation; W1p: r*8192.
// ---------------------------------------------------------------------------
__global__ void pack_w(const float* __restrict__ W0, const float* __restrict__ W1,
                       const float* __restrict__ uW0, const float* __restrict__ uW1,
                       u16t* __restrict__ W0p, u16t* __restrict__ W1p,
                       u16t* __restrict__ U0p, u16t* __restrict__ U1p) {
    int tid = blockIdx.x * 256 + threadIdx.x;
    if (tid < 49152) {                       // W0p [3][4][8][64][8]
        int j = tid & 7, lane = (tid >> 3) & 63, c = (tid >> 9) & 7,
            kk = (tid >> 12) & 3, r = tid >> 14;
        int k = kk * 32 + (lane >> 4) * 8 + j, n = c * 16 + (lane & 15);
        W0p[tid] = f2b(W0[(r * 128 + k) * 128 + n]);
    } else if (tid < 73728) {                // W1p [3][4][4][64][8]
        int t2 = tid - 49152;
        int j = t2 & 7, lane = (t2 >> 3) & 63, c = (t2 >> 9) & 3,
            kk = (t2 >> 11) & 3, r = t2 >> 13;
        int k = kk * 32 + (lane >> 4) * 8 + j, n = c * 16 + (lane & 15);
        W1p[t2] = f2b(W1[(r * 128 + k) * 64 + n]);
    } else if (tid < 90112) {                // U0p [4][8][64][8]
        int t3 = tid - 73728;
        int j = t3 & 7, lane = (t3 >> 3) & 63, c = (t3 >> 9) & 7, kk = t3 >> 12;
        int k = kk * 32 + (lane >> 4) * 8 + j, n = c * 16 + (lane & 15);
        U0p[t3] = f2b(uW0[k * 128 + n]);
    } else if (tid < 98304) {                // U1p [4][4][64][8]
        int t4 = tid - 90112;
        int j = t4 & 7, lane = (t4 >> 3) & 63, c = (t4 >> 9) & 3, kk = t4 >> 11;
        int k = kk * 32 + (lane >> 4) * 8 + j, n = c * 16 + (lane & 15);
        U1p[t4] = f2b(uW1[k * 64 + n]);
    }
}

// ---------------------------------------------------------------------------
// UI MLP via MFMA -> bf16 ui table [8192][64].  256 blocks x 512 thr, 32 rows.
// ---------------------------------------------------------------------------
__global__ __launch_bounds__(512) void prep_ui(
    const float* __restrict__ u_emb, const float* __restrict__ i_emb,
    const u16t* __restrict__ U0p, const u16t* __restrict__ U1p,
    const float* __restrict__ uib0, const float* __restrict__ uib1,
    u16t* __restrict__ uiT)
{
    __shared__ __align__(16) u16t sA[32 * SAP];
    __shared__ __align__(16) u16t sH[32 * SAP];
    const int t = threadIdx.x, wave = t >> 6, lane = t & 63, m = lane & 15, kg = lane >> 4;
    const int c = wave, c2 = wave & 3, hlf = wave >> 2;
    const int B0 = blockIdx.x * 32;

    bf16x8 w0f[4], w1f[4];
#pragma unroll
    for (int kk = 0; kk < 4; ++kk) {
        w0f[kk] = *(const bf16x8*)(U0p + (((kk * 8 + c) * 64 + lane) << 3));
        w1f[kk] = *(const bf16x8*)(U1p + (((kk * 4 + c2) * 64 + lane) << 3));
    }
    const float b0 = uib0[c * 16 + m], b1 = uib1[c2 * 16 + m];

    {   // stage 32 rows of u||i (f32 -> bf16)
        const int row = t >> 4, seg = t & 15;
        const float* src = (seg < 8) ? (u_emb + (size_t)(B0 + row) * 64 + seg * 8)
                                     : (i_emb + (size_t)(B0 + row) * 64 + (seg - 8) * 8);
        float4 v0 = ((const float4*)src)[0], v1 = ((const float4*)src)[1];
        *(uint4*)&sA[row * SAP + seg * 8] = pack8(v0, v1);
    }
    __syncthreads();

#pragma unroll
    for (int mt = 0; mt < 2; ++mt) {
        const u16t* ap = &sA[(mt * 16 + m) * SAP + kg * 8];
        bf16x8 a0 = *(const bf16x8*)(ap),      a1 = *(const bf16x8*)(ap + 32);
        bf16x8 a2 = *(const bf16x8*)(ap + 64), a3 = *(const bf16x8*)(ap + 96);
        f32x4 acc = {0.f, 0.f, 0.f, 0.f};
        acc = __builtin_amdgcn_mfma_f32_16x16x32_bf16(a0, w0f[0], acc, 0, 0, 0);
        acc = __builtin_amdgcn_mfma_f32_16x16x32_bf16(a1, w0f[1], acc, 0, 0, 0);
        acc = __builtin_amdgcn_mfma_f32_16x16x32_bf16(a2, w0f[2], acc, 0, 0, 0);
        acc = __builtin_amdgcn_mfma_f32_16x16x32_bf16(a3, w0f[3], acc, 0, 0, 0);
#pragma unroll
        for (int j = 0; j < 4; ++j)
            sH[(mt * 16 + kg * 4 + j) * SAP + c * 16 + m] = f2b(lrelu(acc[j] + b0));
    }
    __syncthreads();

    {   // L1: wave (hlf,c2) handles tile mt=hlf
        const int mt = hlf;
        const u16t* hp = &sH[(mt * 16 + m) * SAP + kg * 8];
        bf16x8 a0 = *(const bf16x8*)(hp),      a1 = *(const bf16x8*)(hp + 32);
        bf16x8 a2 = *(const bf16x8*)(hp + 64), a3 = *(const bf16x8*)(hp + 96);
        f32x4 acc = {0.f, 0.f, 0.f, 0.f};
        acc = __builtin_amdgcn_mfma_f32_16x16x32_bf16(a0, w1f[0], acc, 0, 0, 0);
        acc = __builtin_amdgcn_mfma_f32_16x16x32_bf16(a1, w1f[1], acc, 0, 0, 0);
        acc = __builtin_amdgcn_mfma_f32_16x16x32_bf16(a2, w1f[2], acc, 0, 0, 0);
        acc = __builtin_amdgcn_mfma_f32_16x16x32_bf16(a3, w1f[3], acc, 0, 0, 0);
#pragma unroll
        for (int j = 0; j < 4; ++j)
            uiT[(size_t)(B0 + mt * 16 + kg * 4 + j) * 64 + c2 * 16 + m] =
                f2b(lrelu(acc[j] + b1));
    }
}

// ---------------------------------------------------------------------------
// Bucketing pass A: per-block relation histograms (256 blocks x 1024 rows).
// ---------------------------------------------------------------------------
__global__ __launch_bounds__(256) void passA(const int* __restrict__ s,
                                             int* __restrict__ cntB) {
    __shared__ int sc[3];
    const int t = threadIdx.x;
    if (t < 3) sc[t] = 0;
    __syncthreads();
    int4 sv = ((const int4*)s)[blockIdx.x * 256 + t];
    int l0 = 0, l1 = 0, l2 = 0;
    int r;
    r = clmp3(sv.x); l0 += (r == 0); l1 += (r == 1); l2 += (r == 2);
    r = clmp3(sv.y); l0 += (r == 0); l1 += (r == 1); l2 += (r == 2);
    r = clmp3(sv.z); l0 += (r == 0); l1 += (r == 1); l2 += (r == 2);
    r = clmp3(sv.w); l0 += (r == 0); l1 += (r == 1); l2 += (r == 2);
    atomicAdd(&sc[0], l0); atomicAdd(&sc[1], l1); atomicAdd(&sc[2], l2);
    __syncthreads();
    if (t < 3) cntB[blockIdx.x * 3 + t] = sc[t];
}

// ---------------------------------------------------------------------------
// Bucketing pass B: exclusive scan + scatter row ids; block 0 writes totals.
// ---------------------------------------------------------------------------
__global__ __launch_bounds__(256) void passB(const int* __restrict__ s,
                                             const int* __restrict__ cntB,
                                             int* __restrict__ cntOut,
                                             int* __restrict__ rows) {
    __shared__ int sTab[768];
    __shared__ int sBT[6];   // [0..2]=block base within bucket, [3..5]=totals
    __shared__ int sS[256];
    const int t = threadIdx.x, blk = blockIdx.x;
    sTab[t] = cntB[t]; sTab[t + 256] = cntB[t + 256]; sTab[t + 512] = cntB[t + 512];
    __syncthreads();
    if (t < 3) {
        int base = 0, tot = 0;
        for (int b = 0; b < 256; ++b) {
            int v = sTab[b * 3 + t];
            if (b < blk) base += v;
            tot += v;
        }
        sBT[t] = base; sBT[3 + t] = tot;
    }
    int4 sv = ((const int4*)s)[blk * 256 + t];
    int rr[4] = { clmp3(sv.x), clmp3(sv.y), clmp3(sv.z), clmp3(sv.w) };
    int packed = (1 << (11 * rr[0])) + (1 << (11 * rr[1]))
               + (1 << (11 * rr[2])) + (1 << (11 * rr[3]));
    sS[t] = packed;
    __syncthreads();
    for (int off = 1; off < 256; off <<= 1) {
        int v = (t >= off) ? sS[t - off] : 0;
        __syncthreads();
        sS[t] += v;
        __syncthreads();
    }
    const int excl = sS[t] - packed;
    const int g0 = 0, g1 = sBT[3], g2 = sBT[3] + sBT[4];
    int seen[3] = {0, 0, 0};
#pragma unroll
    for (int i = 0; i < 4; ++i) {
        int rl = rr[i];
        int gb = rl == 0 ? g0 : (rl == 1 ? g1 : g2);
        int pos = gb + sBT[rl] + ((excl >> (11 * rl)) & 2047) + seen[rl];
        seen[rl]++;
        rows[pos] = blk * 1024 + t * 4 + i;
    }
    if (blk == 0 && t < 3) cntOut[t] = sBT[3 + t];
}

// ---------------------------------------------------------------------------
// AO main: one 64-row single-relation chunk per block.  Weights (1 relation)
// resident in 64 VGPRs; full 16-row M-tiles; 2 barriers; pred via global
// atomicAdd into zeroed out.
// ---------------------------------------------------------------------------
__global__ __launch_bounds__(512) void ao_main(
    const float* __restrict__ a_emb, const float* __restrict__ o_emb,
    const float* __restrict__ ao_b0, const float* __restrict__ ao_b1,
    const u16t* __restrict__ W0p, const u16t* __restrict__ W1p,
    const u16t* __restrict__ uiT, const int* __restrict__ rows,
    const int* __restrict__ tot, float* __restrict__ out)
{
    __shared__ __align__(16) u16t sA[64 * SAP];
    __shared__ __align__(16) u16t sH[64 * SAP];
    __shared__ __align__(16) u16t sUIl[64 * UIP];
    __shared__ int sRid[64];

    const int n0 = tot[0], n1 = tot[1], n2 = tot[2];
    const int ch0 = (n0 + 63) >> 6, ch1 = (n1 + 63) >> 6, ch2 = (n2 + 63) >> 6;
    const int blk = blockIdx.x;
    int r, chunk, bb, nb;
    if (blk < ch0)             { r = 0; chunk = blk;              bb = 0;       nb = n0; }
    else if (blk < ch0 + ch1)  { r = 1; chunk = blk - ch0;        bb = n0;      nb = n1; }
    else if (blk < ch0 + ch1 + ch2) { r = 2; chunk = blk - ch0 - ch1; bb = n0 + n1; nb = n2; }
    else return;
    const int rstart = chunk * 64;
    int nrows = nb - rstart; if (nrows > 64) nrows = 64;

    const int t = threadIdx.x, wave = t >> 6, lane = t & 63, m = lane & 15, kg = lane >> 4;
    const int c = wave, c2 = wave & 3, hlf = wave >> 2;

    // ---- single-relation weight fragments: 8 x bf16x8 = 64 VGPR ----
    const u16t* wp0 = W0p + r * 16384;
    const u16t* wp1 = W1p + r * 8192;
    bf16x8 w0f[4], w1f[4];
#pragma unroll
    for (int kk = 0; kk < 4; ++kk) {
        w0f[kk] = *(const bf16x8*)(wp0 + (((kk * 8 + c) * 64 + lane) << 3));
        w1f[kk] = *(const bf16x8*)(wp1 + (((kk * 4 + c2) * 64 + lane) << 3));
    }
    const float b0 = ao_b0[r * 128 + c * 16 + m];
    const float b1 = ao_b1[r * 64 + c2 * 16 + m];

    // ---- stage: gather rows (a||o f32 -> bf16) + ui rows (bf16, per b) ----
    {
        const int q = t >> 3, seg = t & 7;
        const int rid = rows[bb + rstart + (q < nrows ? q : nrows - 1)];
        const float* src = (seg < 4) ? (a_emb + (size_t)rid * 64 + seg * 16)
                                     : (o_emb + (size_t)rid * 64 + (seg - 4) * 16);
        float4 v0 = ((const float4*)src)[0], v1 = ((const float4*)src)[1];
        float4 v2 = ((const float4*)src)[2], v3 = ((const float4*)src)[3];
        uint4* dst = (uint4*)&sA[q * SAP + seg * 16];
        dst[0] = pack8(v0, v1);
        dst[1] = pack8(v2, v3);
        *(uint4*)&sUIl[q * UIP + seg * 8] =
            *(const uint4*)(uiT + ((size_t)(rid >> 5)) * 64 + seg * 8);   // b = rid/N
        if (t < 64) sRid[t] = rows[bb + rstart + (t < nrows ? t : nrows - 1)];
    }
    __syncthreads();

    // ---- L0 MFMA: h0 = lrelu(ao_in @ W0[r] + b0) -> sH ----
#pragma unroll
    for (int mt = 0; mt < 4; ++mt) {
        const u16t* ap = &sA[(mt * 16 + m) * SAP + kg * 8];
        bf16x8 a0 = *(const bf16x8*)(ap),      a1 = *(const bf16x8*)(ap + 32);
        bf16x8 a2 = *(const bf16x8*)(ap + 64), a3 = *(const bf16x8*)(ap + 96);
        f32x4 acc_a = {0.f, 0.f, 0.f, 0.f}, acc_b = {0.f, 0.f, 0.f, 0.f};
        acc_a = __builtin_amdgcn_mfma_f32_16x16x32_bf16(a0, w0f[0], acc_a, 0, 0, 0);
        acc_a = __builtin_amdgcn_mfma_f32_16x16x32_bf16(a1, w0f[1], acc_a, 0, 0, 0);
        acc_b = __builtin_amdgcn_mfma_f32_16x16x32_bf16(a2, w0f[2], acc_b, 0, 0, 0);
        acc_b = __builtin_amdgcn_mfma_f32_16x16x32_bf16(a3, w0f[3], acc_b, 0, 0, 0);
        f32x4 acc = acc_a + acc_b;
#pragma unroll
        for (int j = 0; j < 4; ++j)
            sH[(mt * 16 + kg * 4 + j) * SAP + c * 16 + m] = f2b(lrelu(acc[j] + b0));
    }
    __syncthreads();

    // ---- L1 MFMA + bias + lrelu + dot(ui, h1) -> global atomicAdd ----
    for (int mt = hlf; mt < 4; mt += 2) {
        const u16t* hp = &sH[(mt * 16 + m) * SAP + kg * 8];
        bf16x8 a0 = *(const bf16x8*)(hp),      a1 = *(const bf16x8*)(hp + 32);
        bf16x8 a2 = *(const bf16x8*)(hp + 64), a3 = *(const bf16x8*)(hp + 96);
        f32x4 acc_a = {0.f, 0.f, 0.f, 0.f}, acc_b = {0.f, 0.f, 0.f, 0.f};
        acc_a = __builtin_amdgcn_mfma_f32_16x16x32_bf16(a0, w1f[0], acc_a, 0, 0, 0);
        acc_a = __builtin_amdgcn_mfma_f32_16x16x32_bf16(a1, w1f[1], acc_a, 0, 0, 0);
        acc_b = __builtin_amdgcn_mfma_f32_16x16x32_bf16(a2, w1f[2], acc_b, 0, 0, 0);
        acc_b = __builtin_amdgcn_mfma_f32_16x16x32_bf16(a3, w1f[3], acc_b, 0, 0, 0);
        f32x4 acc = acc_a + acc_b;
        const int o = c2 * 16 + m;
        float pj[4];
#pragma unroll
        for (int j = 0; j < 4; ++j) {
            const int q = mt * 16 + kg * 4 + j;
            pj[j] = lrelu(acc[j] + b1) * b2f(sUIl[q * UIP + o]);
        }
#pragma unroll
        for (int msk = 8; msk >= 1; msk >>= 1) {
#pragma unroll
            for (int j = 0; j < 4; ++j) pj[j] += __shfl_xor(pj[j], msk, 16);
        }
        if (m == 0) {
#pragma unroll
            for (int j = 0; j < 4; ++j) {
                const int q = mt * 16 + kg * 4 + j;
                if (q < nrows) atomicAdd(&out[sRid[q]], pj[j]);
            }
        }
    }
}

extern "C" void kernel_launch(void* const* d_in, const int* in_sizes, int n_in,
                              void* d_out, int out_size, void* d_ws, size_t ws_size,
                              hipStream_t stream) {
    (void)in_sizes; (void)n_in; (void)ws_size;
    const float* u_emb = (const float*)d_in[0];
    const float* i_emb = (const float*)d_in[1];
    const float* a_emb = (const float*)d_in[2];
    const float* o_emb = (const float*)d_in[3];
    const int*   s     = (const int*)  d_in[4];
    const float* aoW0  = (const float*)d_in[5];
    const float* aob0  = (const float*)d_in[6];
    const float* aoW1  = (const float*)d_in[7];
    const float* aob1  = (const float*)d_in[8];
    const float* uiW0  = (const float*)d_in[9];
    const float* uib0  = (const float*)d_in[10];
    const float* uiW1  = (const float*)d_in[11];
    const float* uib1  = (const float*)d_in[12];
    float* out = (float*)d_out;

    char* ws = (char*)d_ws;
    u16t* W0p  = (u16t*)(ws);                 //  98304 B  (49152 u16)
    u16t* W1p  = (u16t*)(ws + 98304);         //  49152 B  (24576 u16)
    u16t* U0p  = (u16t*)(ws + 147456);        //  32768 B  (16384 u16)
    u16t* U1p  = (u16t*)(ws + 180224);        //  16384 B  ( 8192 u16)
    u16t* uiT  = (u16t*)(ws + 196608);        // 1048576 B (8192*64 u16)
    int*  cntB = (int*) (ws + 1245184);       //   3072 B  (768 int)
    int*  totC = (int*) (ws + 1248256);       //     16 B  (3 int + pad)
    int*  rowsP= (int*) (ws + 1248272);       // 1048576 B (262144 int)

    hipMemsetAsync(d_out, 0, (size_t)out_size * sizeof(float), stream);
    pack_w<<<dim3(384), dim3(256), 0, stream>>>(aoW0, aoW1, uiW0, uiW1, W0p, W1p, U0p, U1p);
    passA<<<dim3(256), dim3(256), 0, stream>>>(s, cntB);
    prep_ui<<<dim3(256), dim3(512), 0, stream>>>(u_emb, i_emb, U0p, U1p, uib0, uib1, uiT);
    passB<<<dim3(256), dim3(256), 0, stream>>>(s, cntB, totC, rowsP);
    ao_main<<<dim3(4099), dim3(512), 0, stream>>>(
        a_emb, o_emb, aob0, aob1, W0p, W1p, uiT, rowsP, totC, out);
}

// Round 6
// 200.137 us; speedup vs baseline: 1.4481x; 1.0789x over previous
//
#include <hip/hip_runtime.h>

typedef unsigned short u16t;
typedef __bf16 bf16x8 __attribute__((ext_vector_type(8)));
typedef float  f32x4  __attribute__((ext_vector_type(4)));

#define SLOPE 0.01f
#define SAP 136   // LDS pitch (u16) for 128-col rows: 272 B, 16B-aligned
#define UIP 72    // LDS pitch (u16) for 64-col ui rows: 144 B, 16B-aligned

__device__ __forceinline__ float lrelu(float x) { return x >= 0.0f ? x : SLOPE * x; }
__device__ __forceinline__ u16t f2b(float f) {
    union { float f; unsigned i; } x; x.f = f;
    return (u16t)((x.i + 0x7fffu + ((x.i >> 16) & 1u)) >> 16);
}
__device__ __forceinline__ float b2f(u16t u) {
    union { unsigned i; float f; } x; x.i = ((unsigned)u) << 16; return x.f;
}
// gfx950 HW packed f32->bf16 (RNE): dst.lo = bf16(a), dst.hi = bf16(b)
__device__ __forceinline__ unsigned pk2(float a, float b) {
    unsigned r;
    asm("v_cvt_pk_bf16_f32 %0, %1, %2" : "=v"(r) : "v"(a), "v"(b));
    return r;
}
__device__ __forceinline__ uint4 pack8(float4 x, float4 y) {
    uint4 r; r.x = pk2(x.x, x.y); r.y = pk2(x.z, x.w);
    r.z = pk2(y.x, y.y); r.w = pk2(y.z, y.w); return r;
}
__device__ __forceinline__ int clmp3(int v) { return v < 0 ? 0 : (v > 2 ? 2 : v); }

// ---------------------------------------------------------------------------
// Kernel A = pack_w (blocks 0..383) + passA histograms (blocks 384..639).
// Pack layout: frag elem j of lane L for (kk, coltile c): B[k][n],
// n=c*16+(L&15), k=kk*32+(L>>4)*8+j.  W0p: r*16384 per relation; W1p: r*8192.
// ---------------------------------------------------------------------------
__global__ __launch_bounds__(256) void kernelA(
    const float* __restrict__ W0, const float* __restrict__ W1,
    const float* __restrict__ uW0, const float* __restrict__ uW1,
    const int* __restrict__ s,
    u16t* __restrict__ W0p, u16t* __restrict__ W1p,
    u16t* __restrict__ U0p, u16t* __restrict__ U1p,
    int* __restrict__ cntB)
{
    __shared__ int sc[3];
    const int t = threadIdx.x;
    if (blockIdx.x < 384) {
        int tid = blockIdx.x * 256 + t;
        if (tid < 49152) {                       // W0p [3][4][8][64][8]
            int j = tid & 7, lane = (tid >> 3) & 63, c = (tid >> 9) & 7,
                kk = (tid >> 12) & 3, r = tid >> 14;
            int k = kk * 32 + (lane >> 4) * 8 + j, n = c * 16 + (lane & 15);
            W0p[tid] = f2b(W0[(r * 128 + k) * 128 + n]);
        } else if (tid < 73728) {                // W1p [3][4][4][64][8]
            int t2 = tid - 49152;
            int j = t2 & 7, lane = (t2 >> 3) & 63, c = (t2 >> 9) & 3,
                kk = (t2 >> 11) & 3, r = t2 >> 13;
            int k = kk * 32 + (lane >> 4) * 8 + j, n = c * 16 + (lane & 15);
            W1p[t2] = f2b(W1[(r * 128 + k) * 64 + n]);
        } else if (tid < 90112) {                // U0p [4][8][64][8]
            int t3 = tid - 73728;
            int j = t3 & 7, lane = (t3 >> 3) & 63, c = (t3 >> 9) & 7, kk = t3 >> 12;
            int k = kk * 32 + (lane >> 4) * 8 + j, n = c * 16 + (lane & 15);
            U0p[t3] = f2b(uW0[k * 128 + n]);
        } else if (tid < 98304) {                // U1p [4][4][64][8]
            int t4 = tid - 90112;
            int j = t4 & 7, lane = (t4 >> 3) & 63, c = (t4 >> 9) & 3, kk = t4 >> 11;
            int k = kk * 32 + (lane >> 4) * 8 + j, n = c * 16 + (lane & 15);
            U1p[t4] = f2b(uW1[k * 64 + n]);
        }
    } else {
        const int blk = blockIdx.x - 384;
        if (t < 3) sc[t] = 0;
        __syncthreads();
        int4 sv = ((const int4*)s)[blk * 256 + t];
        int l0 = 0, l1 = 0, l2 = 0, r;
        r = clmp3(sv.x); l0 += (r == 0); l1 += (r == 1); l2 += (r == 2);
        r = clmp3(sv.y); l0 += (r == 0); l1 += (r == 1); l2 += (r == 2);
        r = clmp3(sv.z); l0 += (r == 0); l1 += (r == 1); l2 += (r == 2);
        r = clmp3(sv.w); l0 += (r == 0); l1 += (r == 1); l2 += (r == 2);
        atomicAdd(&sc[0], l0); atomicAdd(&sc[1], l1); atomicAdd(&sc[2], l2);
        __syncthreads();
        if (t < 3) cntB[blk * 3 + t] = sc[t];
    }
}

// ---------------------------------------------------------------------------
// Kernel B = prep_ui (blocks 0..255, 512 thr) + passB scan/scatter
// (blocks 256..511, first 256 thr active, barriers by all).
// ---------------------------------------------------------------------------
__global__ __launch_bounds__(512) void kernelB(
    const float* __restrict__ u_emb, const float* __restrict__ i_emb,
    const u16t* __restrict__ U0p, const u16t* __restrict__ U1p,
    const float* __restrict__ uib0, const float* __restrict__ uib1,
    const int* __restrict__ s, const int* __restrict__ cntB,
    u16t* __restrict__ uiT, int* __restrict__ cntOut, int* __restrict__ rows)
{
    __shared__ __align__(16) u16t sA[32 * SAP];
    __shared__ __align__(16) u16t sH[32 * SAP];
    __shared__ int sTab[768];
    __shared__ int sBT[6];
    __shared__ int sS[256];
    const int t = threadIdx.x;

    if (blockIdx.x < 256) {
        // ---------------- prep_ui ----------------
        const int wave = t >> 6, lane = t & 63, m = lane & 15, kg = lane >> 4;
        const int c = wave, c2 = wave & 3, hlf = wave >> 2;
        const int B0 = blockIdx.x * 32;

        bf16x8 w0f[4], w1f[4];
#pragma unroll
        for (int kk = 0; kk < 4; ++kk) {
            w0f[kk] = *(const bf16x8*)(U0p + (((kk * 8 + c) * 64 + lane) << 3));
            w1f[kk] = *(const bf16x8*)(U1p + (((kk * 4 + c2) * 64 + lane) << 3));
        }
        const float b0 = uib0[c * 16 + m], b1 = uib1[c2 * 16 + m];

        {   // stage 32 rows of u||i (f32 -> bf16)
            const int row = t >> 4, seg = t & 15;
            const float* src = (seg < 8) ? (u_emb + (size_t)(B0 + row) * 64 + seg * 8)
                                         : (i_emb + (size_t)(B0 + row) * 64 + (seg - 8) * 8);
            float4 v0 = ((const float4*)src)[0], v1 = ((const float4*)src)[1];
            *(uint4*)&sA[row * SAP + seg * 8] = pack8(v0, v1);
        }
        __syncthreads();

#pragma unroll
        for (int mt = 0; mt < 2; ++mt) {
            const u16t* ap = &sA[(mt * 16 + m) * SAP + kg * 8];
            bf16x8 a0 = *(const bf16x8*)(ap),      a1 = *(const bf16x8*)(ap + 32);
            bf16x8 a2 = *(const bf16x8*)(ap + 64), a3 = *(const bf16x8*)(ap + 96);
            f32x4 acc = {0.f, 0.f, 0.f, 0.f};
            acc = __builtin_amdgcn_mfma_f32_16x16x32_bf16(a0, w0f[0], acc, 0, 0, 0);
            acc = __builtin_amdgcn_mfma_f32_16x16x32_bf16(a1, w0f[1], acc, 0, 0, 0);
            acc = __builtin_amdgcn_mfma_f32_16x16x32_bf16(a2, w0f[2], acc, 0, 0, 0);
            acc = __builtin_amdgcn_mfma_f32_16x16x32_bf16(a3, w0f[3], acc, 0, 0, 0);
#pragma unroll
            for (int j = 0; j < 4; ++j)
                sH[(mt * 16 + kg * 4 + j) * SAP + c * 16 + m] = f2b(lrelu(acc[j] + b0));
        }
        __syncthreads();

        {   // L1: wave (hlf,c2) handles tile mt=hlf
            const int mt = hlf;
            const u16t* hp = &sH[(mt * 16 + m) * SAP + kg * 8];
            bf16x8 a0 = *(const bf16x8*)(hp),      a1 = *(const bf16x8*)(hp + 32);
            bf16x8 a2 = *(const bf16x8*)(hp + 64), a3 = *(const bf16x8*)(hp + 96);
            f32x4 acc = {0.f, 0.f, 0.f, 0.f};
            acc = __builtin_amdgcn_mfma_f32_16x16x32_bf16(a0, w1f[0], acc, 0, 0, 0);
            acc = __builtin_amdgcn_mfma_f32_16x16x32_bf16(a1, w1f[1], acc, 0, 0, 0);
            acc = __builtin_amdgcn_mfma_f32_16x16x32_bf16(a2, w1f[2], acc, 0, 0, 0);
            acc = __builtin_amdgcn_mfma_f32_16x16x32_bf16(a3, w1f[3], acc, 0, 0, 0);
#pragma unroll
            for (int j = 0; j < 4; ++j)
                uiT[(size_t)(B0 + mt * 16 + kg * 4 + j) * 64 + c2 * 16 + m] =
                    f2b(lrelu(acc[j] + b1));
        }
    } else {
        // ---------------- passB ----------------
        const int blk = blockIdx.x - 256;
        if (t < 256) {
            sTab[t] = cntB[t]; sTab[t + 256] = cntB[t + 256]; sTab[t + 512] = cntB[t + 512];
        }
        __syncthreads();
        if (t < 3) {
            int base = 0, tot = 0;
            for (int b = 0; b < 256; ++b) {
                int v = sTab[b * 3 + t];
                if (b < blk) base += v;
                tot += v;
            }
            sBT[t] = base; sBT[3 + t] = tot;
        }
        int rr0 = 0, rr1 = 0, rr2 = 0, rr3 = 0, packed = 0;
        if (t < 256) {
            int4 sv = ((const int4*)s)[blk * 256 + t];
            rr0 = clmp3(sv.x); rr1 = clmp3(sv.y); rr2 = clmp3(sv.z); rr3 = clmp3(sv.w);
            packed = (1 << (11 * rr0)) + (1 << (11 * rr1))
                   + (1 << (11 * rr2)) + (1 << (11 * rr3));
            sS[t] = packed;
        }
        __syncthreads();
        for (int off = 1; off < 256; off <<= 1) {
            int v = 0;
            if (t >= off && t < 256) v = sS[t - off];
            __syncthreads();
            if (t < 256) sS[t] += v;
            __syncthreads();
        }
        if (t < 256) {
            const int excl = sS[t] - packed;
            const int g1 = sBT[3], g2 = sBT[3] + sBT[4];
            int rr[4] = { rr0, rr1, rr2, rr3 };
            int seen[3] = {0, 0, 0};
#pragma unroll
            for (int i = 0; i < 4; ++i) {
                int rl = rr[i];
                int gb = rl == 0 ? 0 : (rl == 1 ? g1 : g2);
                int pos = gb + sBT[rl] + ((excl >> (11 * rl)) & 2047) + seen[rl];
                seen[rl]++;
                rows[pos] = blk * 1024 + t * 4 + i;
            }
        }
        if (blk == 0 && t < 3) cntOut[t] = sBT[3 + t];
    }
}

// ---------------------------------------------------------------------------
// AO main: 2 sequential 64-row single-relation chunks per block.  One
// relation's weights resident (64 VGPR); full M-tiles; pred via LDS
// ds_add_f32 + scattered plain stores (no memset, no global atomics).
// ---------------------------------------------------------------------------
__global__ __launch_bounds__(512, 4) void ao_main(
    const float* __restrict__ a_emb, const float* __restrict__ o_emb,
    const float* __restrict__ ao_b0, const float* __restrict__ ao_b1,
    const u16t* __restrict__ W0p, const u16t* __restrict__ W1p,
    const u16t* __restrict__ uiT, const int* __restrict__ rows,
    const int* __restrict__ tot, float* __restrict__ out)
{
    __shared__ __align__(16) u16t sA[64 * SAP];
    __shared__ __align__(16) u16t sH[64 * SAP];
    __shared__ __align__(16) u16t sUIl[64 * UIP];
    __shared__ float sPred[64];

    const int n0 = tot[0], n1 = tot[1], n2 = tot[2];
    const int ch0 = (n0 + 63) >> 6, ch1 = (n1 + 63) >> 6, ch2 = (n2 + 63) >> 6;
    const int nch = ch0 + ch1 + ch2;

    const int t = threadIdx.x, wave = t >> 6, lane = t & 63, m = lane & 15, kg = lane >> 4;
    const int c = wave, c2 = wave & 3, hlf = wave >> 2;

    bf16x8 w0f[4], w1f[4];
    float b0 = 0.f, b1 = 0.f;
    int rprev = -1;

    for (int ci = 0; ci < 2; ++ci) {
        const int chunk = blockIdx.x * 2 + ci;
        if (chunk >= nch) break;                       // block-uniform
        int r, rel, bb, nb;
        if (chunk < ch0)            { r = 0; rel = chunk;             bb = 0;       nb = n0; }
        else if (chunk < ch0 + ch1) { r = 1; rel = chunk - ch0;       bb = n0;      nb = n1; }
        else                        { r = 2; rel = chunk - ch0 - ch1; bb = n0 + n1; nb = n2; }
        const int rstart = rel * 64;
        int nrows = nb - rstart; if (nrows > 64) nrows = 64;

        if (r != rprev) {            // block-uniform; taken once for most blocks
            const u16t* wp0 = W0p + r * 16384;
            const u16t* wp1 = W1p + r * 8192;
#pragma unroll
            for (int kk = 0; kk < 4; ++kk) {
                w0f[kk] = *(const bf16x8*)(wp0 + (((kk * 8 + c) * 64 + lane) << 3));
                w1f[kk] = *(const bf16x8*)(wp1 + (((kk * 4 + c2) * 64 + lane) << 3));
            }
            b0 = ao_b0[r * 128 + c * 16 + m];
            b1 = ao_b1[r * 64 + c2 * 16 + m];
            rprev = r;
        }

        // ---- S: gather rows (a||o f32 -> bf16) + ui rows; init sPred ----
        {
            const int q = t >> 3, seg = t & 7;
            const int rid = rows[bb + rstart + (q < nrows ? q : nrows - 1)];
            const float* src = (seg < 4) ? (a_emb + (size_t)rid * 64 + seg * 16)
                                         : (o_emb + (size_t)rid * 64 + (seg - 4) * 16);
            float4 v0 = ((const float4*)src)[0], v1 = ((const float4*)src)[1];
            float4 v2 = ((const float4*)src)[2], v3 = ((const float4*)src)[3];
            uint4* dst = (uint4*)&sA[q * SAP + seg * 16];
            dst[0] = pack8(v0, v1);
            dst[1] = pack8(v2, v3);
            *(uint4*)&sUIl[q * UIP + seg * 8] =
                *(const uint4*)(uiT + ((size_t)(rid >> 5)) * 64 + seg * 8);  // b = rid/N
        }
        if (t < 64) sPred[t] = 0.0f;
        __syncthreads();

        // ---- L0 MFMA: h0 = lrelu(ao_in @ W0[r] + b0) -> sH ----
#pragma unroll
        for (int mt = 0; mt < 4; ++mt) {
            const u16t* ap = &sA[(mt * 16 + m) * SAP + kg * 8];
            bf16x8 a0 = *(const bf16x8*)(ap),      a1 = *(const bf16x8*)(ap + 32);
            bf16x8 a2 = *(const bf16x8*)(ap + 64), a3 = *(const bf16x8*)(ap + 96);
            f32x4 acc_a = {0.f, 0.f, 0.f, 0.f}, acc_b = {0.f, 0.f, 0.f, 0.f};
            acc_a = __builtin_amdgcn_mfma_f32_16x16x32_bf16(a0, w0f[0], acc_a, 0, 0, 0);
            acc_a = __builtin_amdgcn_mfma_f32_16x16x32_bf16(a1, w0f[1], acc_a, 0, 0, 0);
            acc_b = __builtin_amdgcn_mfma_f32_16x16x32_bf16(a2, w0f[2], acc_b, 0, 0, 0);
            acc_b = __builtin_amdgcn_mfma_f32_16x16x32_bf16(a3, w0f[3], acc_b, 0, 0, 0);
            f32x4 acc = acc_a + acc_b;
#pragma unroll
            for (int j = 0; j < 4; ++j)
                sH[(mt * 16 + kg * 4 + j) * SAP + c * 16 + m] = f2b(lrelu(acc[j] + b0));
        }
        __syncthreads();

        // ---- L1 MFMA + bias + lrelu + dot(ui, h1) -> LDS ds_add_f32 ----
        for (int mt = hlf; mt < 4; mt += 2) {
            const u16t* hp = &sH[(mt * 16 + m) * SAP + kg * 8];
            bf16x8 a0 = *(const bf16x8*)(hp),      a1 = *(const bf16x8*)(hp + 32);
            bf16x8 a2 = *(const bf16x8*)(hp + 64), a3 = *(const bf16x8*)(hp + 96);
            f32x4 acc_a = {0.f, 0.f, 0.f, 0.f}, acc_b = {0.f, 0.f, 0.f, 0.f};
            acc_a = __builtin_amdgcn_mfma_f32_16x16x32_bf16(a0, w1f[0], acc_a, 0, 0, 0);
            acc_a = __builtin_amdgcn_mfma_f32_16x16x32_bf16(a1, w1f[1], acc_a, 0, 0, 0);
            acc_b = __builtin_amdgcn_mfma_f32_16x16x32_bf16(a2, w1f[2], acc_b, 0, 0, 0);
            acc_b = __builtin_amdgcn_mfma_f32_16x16x32_bf16(a3, w1f[3], acc_b, 0, 0, 0);
            f32x4 acc = acc_a + acc_b;
            const int o = c2 * 16 + m;
            float pj[4];
#pragma unroll
            for (int j = 0; j < 4; ++j) {
                const int q = mt * 16 + kg * 4 + j;
                pj[j] = lrelu(acc[j] + b1) * b2f(sUIl[q * UIP + o]);
            }
#pragma unroll
            for (int msk = 8; msk >= 1; msk >>= 1) {
#pragma unroll
                for (int j = 0; j < 4; ++j) pj[j] += __shfl_xor(pj[j], msk, 16);
            }
            if (m == 0) {
#pragma unroll
                for (int j = 0; j < 4; ++j)
                    atomicAdd(&sPred[mt * 16 + kg * 4 + j], pj[j]);
            }
        }
        __syncthreads();

        // ---- W: scattered plain stores (each out element written once) ----
        if (t < nrows) out[rows[bb + rstart + t]] = sPred[t];
    }
}

extern "C" void kernel_launch(void* const* d_in, const int* in_sizes, int n_in,
                              void* d_out, int out_size, void* d_ws, size_t ws_size,
                              hipStream_t stream) {
    (void)in_sizes; (void)n_in; (void)out_size; (void)ws_size;
    const float* u_emb = (const float*)d_in[0];
    const float* i_emb = (const float*)d_in[1];
    const float* a_emb = (const float*)d_in[2];
    const float* o_emb = (const float*)d_in[3];
    const int*   s     = (const int*)  d_in[4];
    const float* aoW0  = (const float*)d_in[5];
    const float* aob0  = (const float*)d_in[6];
    const float* aoW1  = (const float*)d_in[7];
    const float* aob1  = (const float*)d_in[8];
    const float* uiW0  = (const float*)d_in[9];
    const float* uib0  = (const float*)d_in[10];
    const float* uiW1  = (const float*)d_in[11];
    const float* uib1  = (const float*)d_in[12];
    float* out = (float*)d_out;

    char* ws = (char*)d_ws;
    u16t* W0p  = (u16t*)(ws);                 //  98304 B
    u16t* W1p  = (u16t*)(ws + 98304);         //  49152 B
    u16t* U0p  = (u16t*)(ws + 147456);        //  32768 B
    u16t* U1p  = (u16t*)(ws + 180224);        //  16384 B
    u16t* uiT  = (u16t*)(ws + 196608);        // 1048576 B (8192*64 bf16)
    int*  cntB = (int*) (ws + 1245184);       //   3072 B
    int*  totC = (int*) (ws + 1248256);       //     16 B
    int*  rowsP= (int*) (ws + 1248272);       // 1048576 B (262144 int)

    kernelA<<<dim3(640), dim3(256), 0, stream>>>(
        aoW0, aoW1, uiW0, uiW1, s, W0p, W1p, U0p, U1p, cntB);
    kernelB<<<dim3(512), dim3(512), 0, stream>>>(
        u_emb, i_emb, U0p, U1p, uib0, uib1, s, cntB, uiT, totC, rowsP);
    ao_main<<<dim3(2051), dim3(512), 0, stream>>>(
        a_emb, o_emb, aob0, aob1, W0p, W1p, uiT, rowsP, totC, out);
}